// Round 2
// baseline (266.886 us; speedup 1.0000x reference)
//
#include <hip/hip_runtime.h>

#define B_ 2
#define C_ 512
#define H_ 50
#define W_ 75
#define N_ 2000
#define SS (1.0f/16.0f)

#define SB (H_ * W_ * C_)   // batch stride (floats), NHWC
#define SH (W_ * C_)        // row stride
#define SW (C_)             // col stride

// (B,C,H,W) -> (B,H,W,C) tiled transpose, 32x32 tiles, 32x8 threads
__global__ __launch_bounds__(256) void transpose_k(const float* __restrict__ in,
                                                   float* __restrict__ out) {
    __shared__ float tile[32][33];
    const int b   = blockIdx.z;
    const int hw0 = blockIdx.x * 32;
    const int c0  = blockIdx.y * 32;
    const int tx  = threadIdx.x;
    const int ty  = threadIdx.y;
    #pragma unroll
    for (int r = 0; r < 32; r += 8) {
        int c  = c0 + ty + r;
        int hw = hw0 + tx;
        if (c < C_ && hw < H_ * W_)
            tile[ty + r][tx] = in[(b * C_ + c) * (H_ * W_) + hw];
    }
    __syncthreads();
    #pragma unroll
    for (int r = 0; r < 32; r += 8) {
        int hw = hw0 + ty + r;
        int c  = c0 + tx;
        if (hw < H_ * W_ && c < C_)
            out[(b * (H_ * W_) + hw) * C_ + c] = tile[tx][ty + r];
    }
}

// One block per roi. 256 threads = 4 waves. Each wave owns 16 samples,
// processes 2 samples per iteration (half-wave each), lane owns 2 channels
// (float2). 8 chunks of 64 channels.
__global__ __launch_bounds__(256) void roi_avg_v2(
    const float* __restrict__ ft, const float* __restrict__ rois,
    float* __restrict__ out)
{
    __shared__ float  sval[64 * 66];   // [sample][64ch], stride 66: phase3 2-way max (free)
    __shared__ float4 swt[64];
    __shared__ int    soff[64];

    const int n   = blockIdx.x;
    const int tid = threadIdx.x;

    if (tid < 64) {
        const int s = tid;
        const int j = s >> 3;
        const int i = s & 7;
        const float bf = rois[n * 5 + 0];
        const float x1 = rois[n * 5 + 1] * SS;
        const float y1 = rois[n * 5 + 2] * SS;
        const float x2 = rois[n * 5 + 3] * SS;
        const float y2 = rois[n * 5 + 4] * SS;
        const int b = (int)bf;
        const float roi_w = fmaxf(x2 - x1 + 1.0f, 0.0f);
        const float roi_h = fmaxf(y2 - y1 + 1.0f, 0.0f);
        const float bin_h = roi_h / 7.0f;
        const float bin_w = roi_w / 7.0f;
        const float h = y1 + (float)j * bin_h;
        const float w = x1 + (float)i * bin_w;
        const bool valid = (h >= 0.0f) && (h < (float)H_) &&
                           (w >= 0.0f) && (w < (float)W_);
        int hs = (int)floorf(h); hs = hs < 0 ? 0 : (hs > H_ - 2 ? H_ - 2 : hs);
        int ws = (int)floorf(w); ws = ws < 0 ? 0 : (ws > W_ - 2 ? W_ - 2 : ws);
        const float hr = h - (float)hs;
        const float wr = w - (float)ws;
        const float vz = valid ? 1.0f : 0.0f;
        float4 wt;
        wt.x = (1.0f - hr) * (1.0f - wr) * vz;
        wt.y = (1.0f - hr) * wr * vz;
        wt.z = hr * (1.0f - wr) * vz;
        wt.w = hr * wr * vz;
        swt[s]  = wt;
        soff[s] = b * SB + hs * SH + ws * SW;
    }
    __syncthreads();

    const int lane = tid & 63;
    const int wv   = tid >> 6;
    const int half = lane >> 5;        // which of 2 samples this half-wave does
    const int l    = lane & 31;        // channel-pair index within chunk
    float2* const sv2 = (float2*)sval;

    for (int chunk = 0; chunk < 8; ++chunk) {
        const int cbase = chunk * 64 + 2 * l;
        #pragma unroll 4
        for (int k = 0; k < 8; ++k) {
            const int s = wv * 16 + 2 * k + half;
            const float4 wt = swt[s];
            const float2* p = (const float2*)(ft + (soff[s] + cbase));
            const float2 v0 = p[0];            // ul  (ch pair contiguous: coalesced)
            const float2 v1 = p[SW / 2];       // ur  (+C floats)
            const float2 v2 = p[SH / 2];       // ll  (+W*C floats)
            const float2 v3 = p[(SH + SW) / 2];// lr
            float2 v;
            v.x = v0.x * wt.x + v1.x * wt.y + v2.x * wt.z + v3.x * wt.w;
            v.y = v0.y * wt.x + v1.y * wt.y + v2.y * wt.z + v3.y * wt.w;
            sv2[s * 33 + l] = v;               // (s*66 + 2l): 8B-aligned, conflict-light
        }
        __syncthreads();
        const int out_base = n * (C_ * 49) + chunk * (64 * 49);
        #pragma unroll
        for (int r = 0; r < 13; ++r) {
            const int o = r * 256 + tid;
            if (o < 64 * 49) {
                const int c  = o / 49;
                const int ji = o - c * 49;
                const int jj = ji / 7;
                const int s  = ji + jj;        // j*8+i == (j*7+i)+j
                const float v = 0.25f * (sval[s * 66 + c]       + sval[(s + 1) * 66 + c] +
                                         sval[(s + 8) * 66 + c] + sval[(s + 9) * 66 + c]);
                out[out_base + o] = v;         // contiguous per (roi,chunk): coalesced
            }
        }
        __syncthreads();
    }
}

// Fallback: generic-stride scalar version (used only if ws too small to transpose)
__global__ __launch_bounds__(256) void roi_avg_generic(
    const float* __restrict__ ft, const float* __restrict__ rois,
    float* __restrict__ out, int sB, int sH, int sW, int sC)
{
    __shared__ float  sval[64 * 65];
    __shared__ float4 swt[64];
    __shared__ int    soff[64];
    const int n   = blockIdx.x;
    const int tid = threadIdx.x;
    if (tid < 64) {
        const int s = tid;
        const int j = s >> 3;
        const int i = s & 7;
        const float bf = rois[n * 5 + 0];
        const float x1 = rois[n * 5 + 1] * SS;
        const float y1 = rois[n * 5 + 2] * SS;
        const float x2 = rois[n * 5 + 3] * SS;
        const float y2 = rois[n * 5 + 4] * SS;
        const int b = (int)bf;
        const float roi_w = fmaxf(x2 - x1 + 1.0f, 0.0f);
        const float roi_h = fmaxf(y2 - y1 + 1.0f, 0.0f);
        const float h = y1 + (float)j * (roi_h / 7.0f);
        const float w = x1 + (float)i * (roi_w / 7.0f);
        const bool valid = (h >= 0.0f) && (h < (float)H_) && (w >= 0.0f) && (w < (float)W_);
        int hs = (int)floorf(h); hs = hs < 0 ? 0 : (hs > H_ - 2 ? H_ - 2 : hs);
        int ws = (int)floorf(w); ws = ws < 0 ? 0 : (ws > W_ - 2 ? W_ - 2 : ws);
        const float hr = h - (float)hs;
        const float wr = w - (float)ws;
        const float vz = valid ? 1.0f : 0.0f;
        float4 wt;
        wt.x = (1.0f - hr) * (1.0f - wr) * vz;
        wt.y = (1.0f - hr) * wr * vz;
        wt.z = hr * (1.0f - wr) * vz;
        wt.w = hr * wr * vz;
        swt[s]  = wt;
        soff[s] = b * sB + hs * sH + ws * sW;
    }
    __syncthreads();
    const int lane = tid & 63;
    const int wv   = tid >> 6;
    for (int chunk = 0; chunk < C_ / 64; ++chunk) {
        const int cbase = (chunk * 64 + lane) * sC;
        #pragma unroll 4
        for (int k = 0; k < 16; ++k) {
            const int s = wv * 16 + k;
            const float4 wt = swt[s];
            const int off = soff[s] + cbase;
            const float v = ft[off]            * wt.x + ft[off + sW]      * wt.y +
                            ft[off + sH]       * wt.z + ft[off + sH + sW] * wt.w;
            sval[s * 65 + lane] = v;
        }
        __syncthreads();
        const int out_base = n * (C_ * 49) + chunk * (64 * 49);
        #pragma unroll
        for (int r = 0; r < 13; ++r) {
            const int o = r * 256 + tid;
            if (o < 64 * 49) {
                const int c  = o / 49;
                const int ji = o - c * 49;
                const int jj = ji / 7;
                const int s  = ji + jj;
                out[out_base + o] = 0.25f * (sval[s * 65 + c]       + sval[(s + 1) * 65 + c] +
                                             sval[(s + 8) * 65 + c] + sval[(s + 9) * 65 + c]);
            }
        }
        __syncthreads();
    }
}

extern "C" void kernel_launch(void* const* d_in, const int* in_sizes, int n_in,
                              void* d_out, int out_size, void* d_ws, size_t ws_size,
                              hipStream_t stream) {
    const float* features = (const float*)d_in[0];
    const float* rois     = (const float*)d_in[1];
    float* out            = (float*)d_out;

    const size_t need = (size_t)B_ * C_ * H_ * W_ * sizeof(float);
    if (ws_size >= need) {
        float* ftT = (float*)d_ws;
        dim3 g((H_ * W_ + 31) / 32, (C_ + 31) / 32, B_);
        dim3 b(32, 8, 1);
        transpose_k<<<g, b, 0, stream>>>(features, ftT);
        roi_avg_v2<<<N_, 256, 0, stream>>>(ftT, rois, out);
    } else {
        roi_avg_generic<<<N_, 256, 0, stream>>>(features, rois, out,
                                                C_ * H_ * W_, W_, 1, H_ * W_);
    }
}

// Round 3
// 240.839 us; speedup vs baseline: 1.1082x; 1.1082x over previous
//
#include <hip/hip_runtime.h>
#include <hip/hip_bf16.h>

#define B_ 2
#define C_ 512
#define H_ 50
#define W_ 75
#define N_ 2000
#define SS (1.0f/16.0f)

#define SB (H_ * W_ * C_)   // batch stride (elements), NHWC
#define SH (W_ * C_)        // row stride
#define SW (C_)             // col stride

__device__ __forceinline__ float bf2f(unsigned short u) {
    union { unsigned i; float f; } c; c.i = (unsigned)u << 16; return c.f;
}

// fused transpose+convert: (B,C,H,W) fp32 -> (B,H,W,C) bf16
__global__ __launch_bounds__(256) void transcvt_k(const float* __restrict__ in,
                                                  __hip_bfloat16* __restrict__ out) {
    __shared__ float tile[32][33];
    const int b   = blockIdx.z;
    const int hw0 = blockIdx.x * 32;
    const int c0  = blockIdx.y * 32;
    const int tx  = threadIdx.x;
    const int ty  = threadIdx.y;
    #pragma unroll
    for (int r = 0; r < 32; r += 8) {
        int c  = c0 + ty + r;
        int hw = hw0 + tx;
        if (c < C_ && hw < H_ * W_)
            tile[ty + r][tx] = in[(b * C_ + c) * (H_ * W_) + hw];
    }
    __syncthreads();
    #pragma unroll
    for (int r = 0; r < 32; r += 8) {
        int hw = hw0 + ty + r;
        int c  = c0 + tx;
        if (hw < H_ * W_ && c < C_)
            out[(b * (H_ * W_) + hw) * C_ + c] = __float2bfloat16(tile[tx][ty + r]);
    }
}

// One block per roi. 256 threads = 4 waves; wave handles 16 samples.
// Per iteration a wave does 4 samples: 16 lanes/sample, lane owns 4 channels
// (ushort4 = 8B load per corner). 8 chunks of 64 channels.
__global__ __launch_bounds__(256) void roi_avg_v3(
    const __hip_bfloat16* __restrict__ ftb, const float* __restrict__ rois,
    float* __restrict__ out)
{
    __shared__ float  sval[64 * 68];   // [sample][64ch], stride 68 (quad-aligned pad)
    __shared__ float4 swt[64];
    __shared__ int    soff[64];

    const int n   = blockIdx.x;
    const int tid = threadIdx.x;

    if (tid < 64) {
        const int s = tid;
        const int j = s >> 3;
        const int i = s & 7;
        const float bfv = rois[n * 5 + 0];
        const float x1 = rois[n * 5 + 1] * SS;
        const float y1 = rois[n * 5 + 2] * SS;
        const float x2 = rois[n * 5 + 3] * SS;
        const float y2 = rois[n * 5 + 4] * SS;
        const int b = (int)bfv;
        const float roi_w = fmaxf(x2 - x1 + 1.0f, 0.0f);
        const float roi_h = fmaxf(y2 - y1 + 1.0f, 0.0f);
        const float h = y1 + (float)j * (roi_h / 7.0f);
        const float w = x1 + (float)i * (roi_w / 7.0f);
        const bool valid = (h >= 0.0f) && (h < (float)H_) &&
                           (w >= 0.0f) && (w < (float)W_);
        int hs = (int)floorf(h); hs = hs < 0 ? 0 : (hs > H_ - 2 ? H_ - 2 : hs);
        int ws = (int)floorf(w); ws = ws < 0 ? 0 : (ws > W_ - 2 ? W_ - 2 : ws);
        const float hr = h - (float)hs;
        const float wr = w - (float)ws;
        const float vz = valid ? 1.0f : 0.0f;
        float4 wt;
        wt.x = (1.0f - hr) * (1.0f - wr) * vz;
        wt.y = (1.0f - hr) * wr * vz;
        wt.z = hr * (1.0f - wr) * vz;
        wt.w = hr * wr * vz;
        swt[s]  = wt;
        soff[s] = b * SB + hs * SH + ws * SW;
    }
    __syncthreads();

    const unsigned short* const ft = (const unsigned short*)ftb;
    const int lane = tid & 63;
    const int wv   = tid >> 6;
    const int q    = lane >> 4;        // sample sub-index 0..3
    const int l    = lane & 15;        // channel-quad index

    for (int chunk = 0; chunk < 8; ++chunk) {
        const int cbase = chunk * 64 + l * 4;
        #pragma unroll
        for (int k = 0; k < 4; ++k) {
            const int s = wv * 16 + k * 4 + q;
            const float4 wt = swt[s];
            const unsigned short* p = ft + soff[s] + cbase;
            const ushort4 a = *(const ushort4*)(p);
            const ushort4 bq = *(const ushort4*)(p + SW);
            const ushort4 c = *(const ushort4*)(p + SH);
            const ushort4 d = *(const ushort4*)(p + SH + SW);
            float4 v;
            v.x = bf2f(a.x) * wt.x + bf2f(bq.x) * wt.y + bf2f(c.x) * wt.z + bf2f(d.x) * wt.w;
            v.y = bf2f(a.y) * wt.x + bf2f(bq.y) * wt.y + bf2f(c.y) * wt.z + bf2f(d.y) * wt.w;
            v.z = bf2f(a.z) * wt.x + bf2f(bq.z) * wt.y + bf2f(c.z) * wt.z + bf2f(d.z) * wt.w;
            v.w = bf2f(a.w) * wt.x + bf2f(bq.w) * wt.y + bf2f(c.w) * wt.z + bf2f(d.w) * wt.w;
            *(float4*)&sval[s * 68 + l * 4] = v;   // ds_write_b128
        }
        __syncthreads();
        const int out_base = n * (C_ * 49) + chunk * (64 * 49);
        #pragma unroll
        for (int r = 0; r < 13; ++r) {
            const int o = r * 256 + tid;
            if (o < 64 * 49) {
                const int c  = o / 49;
                const int ji = o - c * 49;
                const int jj = ji / 7;
                const int s  = ji + jj;    // j*8+i == (j*7+i)+j
                const float v = 0.25f * (sval[s * 68 + c]       + sval[(s + 1) * 68 + c] +
                                         sval[(s + 8) * 68 + c] + sval[(s + 9) * 68 + c]);
                out[out_base + o] = v;     // contiguous per (roi,chunk): coalesced
            }
        }
        __syncthreads();
    }
}

// Fallback: fp32 native-layout version (only if ws too small)
__global__ __launch_bounds__(256) void roi_avg_generic(
    const float* __restrict__ ft, const float* __restrict__ rois,
    float* __restrict__ out, int sB, int sH, int sW, int sC)
{
    __shared__ float  sval[64 * 65];
    __shared__ float4 swt[64];
    __shared__ int    soff[64];
    const int n   = blockIdx.x;
    const int tid = threadIdx.x;
    if (tid < 64) {
        const int s = tid;
        const int j = s >> 3;
        const int i = s & 7;
        const float bfv = rois[n * 5 + 0];
        const float x1 = rois[n * 5 + 1] * SS;
        const float y1 = rois[n * 5 + 2] * SS;
        const float x2 = rois[n * 5 + 3] * SS;
        const float y2 = rois[n * 5 + 4] * SS;
        const int b = (int)bfv;
        const float roi_w = fmaxf(x2 - x1 + 1.0f, 0.0f);
        const float roi_h = fmaxf(y2 - y1 + 1.0f, 0.0f);
        const float h = y1 + (float)j * (roi_h / 7.0f);
        const float w = x1 + (float)i * (roi_w / 7.0f);
        const bool valid = (h >= 0.0f) && (h < (float)H_) && (w >= 0.0f) && (w < (float)W_);
        int hs = (int)floorf(h); hs = hs < 0 ? 0 : (hs > H_ - 2 ? H_ - 2 : hs);
        int ws = (int)floorf(w); ws = ws < 0 ? 0 : (ws > W_ - 2 ? W_ - 2 : ws);
        const float hr = h - (float)hs;
        const float wr = w - (float)ws;
        const float vz = valid ? 1.0f : 0.0f;
        float4 wt;
        wt.x = (1.0f - hr) * (1.0f - wr) * vz;
        wt.y = (1.0f - hr) * wr * vz;
        wt.z = hr * (1.0f - wr) * vz;
        wt.w = hr * wr * vz;
        swt[s]  = wt;
        soff[s] = b * sB + hs * sH + ws * sW;
    }
    __syncthreads();
    const int lane = tid & 63;
    const int wv   = tid >> 6;
    for (int chunk = 0; chunk < C_ / 64; ++chunk) {
        const int cbase = (chunk * 64 + lane) * sC;
        #pragma unroll 4
        for (int k = 0; k < 16; ++k) {
            const int s = wv * 16 + k;
            const float4 wt = swt[s];
            const int off = soff[s] + cbase;
            sval[s * 65 + lane] = ft[off]            * wt.x + ft[off + sW]      * wt.y +
                                  ft[off + sH]       * wt.z + ft[off + sH + sW] * wt.w;
        }
        __syncthreads();
        const int out_base = n * (C_ * 49) + chunk * (64 * 49);
        #pragma unroll
        for (int r = 0; r < 13; ++r) {
            const int o = r * 256 + tid;
            if (o < 64 * 49) {
                const int c  = o / 49;
                const int ji = o - c * 49;
                const int jj = ji / 7;
                const int s  = ji + jj;
                out[out_base + o] = 0.25f * (sval[s * 65 + c]       + sval[(s + 1) * 65 + c] +
                                             sval[(s + 8) * 65 + c] + sval[(s + 9) * 65 + c]);
            }
        }
        __syncthreads();
    }
}

extern "C" void kernel_launch(void* const* d_in, const int* in_sizes, int n_in,
                              void* d_out, int out_size, void* d_ws, size_t ws_size,
                              hipStream_t stream) {
    const float* features = (const float*)d_in[0];
    const float* rois     = (const float*)d_in[1];
    float* out            = (float*)d_out;

    const size_t need = (size_t)B_ * C_ * H_ * W_ * sizeof(__hip_bfloat16);
    if (ws_size >= need) {
        __hip_bfloat16* ftb = (__hip_bfloat16*)d_ws;
        dim3 g((H_ * W_ + 31) / 32, (C_ + 31) / 32, B_);
        dim3 b(32, 8, 1);
        transcvt_k<<<g, b, 0, stream>>>(features, ftb);
        roi_avg_v3<<<N_, 256, 0, stream>>>(ftb, rois, out);
    } else {
        roi_avg_generic<<<N_, 256, 0, stream>>>(features, rois, out,
                                                C_ * H_ * W_, W_, 1, H_ * W_);
    }
}